// Round 4
// baseline (251.759 us; speedup 1.0000x reference)
//
#include <hip/hip_runtime.h>

#define BGR 8
#define VG  20000
#define NK  128
#define ND  128

typedef float f32x4 __attribute__((ext_vector_type(4)));
typedef short bf16x8 __attribute__((ext_vector_type(8)));

// Raw barrier: waits LDS ops only, leaves global loads IN FLIGHT.
// __syncthreads() lowers to s_waitcnt vmcnt(0) lgkmcnt(0) + s_barrier, which
// drains the global-load queue at every barrier and killed all prefetching
// (three structurally different k_spec versions all pinned at ~80us).
#define BAR() do {                                          \
    asm volatile("s_waitcnt lgkmcnt(0)" ::: "memory");      \
    __builtin_amdgcn_s_barrier();                           \
    asm volatile("" ::: "memory");                          \
} while (0)

// two fp32 -> packed 2x bf16 (RNE) in one instruction
__device__ __forceinline__ unsigned cvtpk(float a, float b) {
    unsigned r;
    asm("v_cvt_pk_bf16_f32 %0, %1, %2" : "=v"(r) : "v"(a), "v"(b));
    return r;
}

// fp32 -> bf16 bits, round-to-nearest-even (scalar, for k_coef)
__device__ __forceinline__ short bf16r(float f) {
    union { float f; unsigned u; } c; c.f = f;
    unsigned r = (c.u + 0x7FFFu + ((c.u >> 16) & 1u)) >> 16;
    return (short)r;
}

// ---------------------------------------------------------------------------
// Kernel 1: partial[bid][d][k] = sum_{v in 160-chunk} (m*x)[v,d] * E[v,k]
// Register ping-pong + issue-ahead; with raw barriers the round-(r+1) loads
// now actually stay in flight across the pack/MFMA of round r (counted vmcnt
// from compiler register deps, never a drain-to-0).
// ---------------------------------------------------------------------------
#define VC  160
#define S1  40
#define NCH (VG / VC)   // 125

__global__ __launch_bounds__(256) void k_spec(const float* __restrict__ x,
                                              const float* __restrict__ mass,
                                              const float* __restrict__ evecs,
                                              float* __restrict__ scr) {
    const int bid   = blockIdx.x;
    const int g     = bid & 7;        // XCD pin
    const int chunk = bid >> 3;
    const int v0    = chunk * VC;

    const float* xg = x     + (size_t)g * VG * ND;
    const float* eg = evecs + (size_t)g * VG * NK;
    const float* mg = mass  + (size_t)g * VG;

    __shared__ short Et[NK * S1];  // [k][v] bf16, octet-swizzled
    __shared__ short Xt[ND * S1];  // [d][v] bf16, octet-swizzled
    __shared__ float Ms[VC];

    const int tid = threadIdx.x;
    const int l   = tid & 63;
    const int w   = tid >> 6;
    const int lo  = l & 15, hi = l >> 4;
    const int r0  = (w & 1) * 64, c0 = (w >> 1) * 64;
    const int oc  = w;                       // v-octet owned by this wave
    const int C0  = 2 * l;                   // col pair owned by this lane
    const int sw  = ((oc ^ ((l >> 2) & 3)) << 3);  // swizzled octet slot (shorts)

    if (tid < VC) Ms[tid] = mg[v0 + tid];

    float2 e0[8], x0[8], e1[8], x1[8];

#define ISSUE_SPEC(EB, XB, r) do {                                          \
    const int vb_ = v0 + (r) * 32 + oc * 8;                                 \
    _Pragma("unroll")                                                       \
    for (int q = 0; q < 8; ++q) {                                           \
        EB[q] = *(const float2*)(eg + (size_t)(vb_ + q) * NK + C0);         \
        XB[q] = *(const float2*)(xg + (size_t)(vb_ + q) * ND + C0);         \
    } } while (0)

#define PACK_SPEC(EB, XB, r) do {                                           \
    const int mb_ = (r) * 32 + oc * 8;                                      \
    float m_[8];                                                            \
    _Pragma("unroll")                                                       \
    for (int q = 0; q < 8; ++q) m_[q] = Ms[mb_ + q];                        \
    uint4 u_;                                                               \
    u_.x = cvtpk(EB[0].x, EB[1].x); u_.y = cvtpk(EB[2].x, EB[3].x);         \
    u_.z = cvtpk(EB[4].x, EB[5].x); u_.w = cvtpk(EB[6].x, EB[7].x);         \
    *(uint4*)(Et + C0 * S1 + sw) = u_;                                      \
    u_.x = cvtpk(EB[0].y, EB[1].y); u_.y = cvtpk(EB[2].y, EB[3].y);         \
    u_.z = cvtpk(EB[4].y, EB[5].y); u_.w = cvtpk(EB[6].y, EB[7].y);         \
    *(uint4*)(Et + (C0 + 1) * S1 + sw) = u_;                                \
    u_.x = cvtpk(XB[0].x * m_[0], XB[1].x * m_[1]);                         \
    u_.y = cvtpk(XB[2].x * m_[2], XB[3].x * m_[3]);                         \
    u_.z = cvtpk(XB[4].x * m_[4], XB[5].x * m_[5]);                         \
    u_.w = cvtpk(XB[6].x * m_[6], XB[7].x * m_[7]);                         \
    *(uint4*)(Xt + C0 * S1 + sw) = u_;                                      \
    u_.x = cvtpk(XB[0].y * m_[0], XB[1].y * m_[1]);                         \
    u_.y = cvtpk(XB[2].y * m_[2], XB[3].y * m_[3]);                         \
    u_.z = cvtpk(XB[4].y * m_[4], XB[5].y * m_[5]);                         \
    u_.w = cvtpk(XB[6].y * m_[6], XB[7].y * m_[7]);                         \
    *(uint4*)(Xt + (C0 + 1) * S1 + sw) = u_;                                \
    } while (0)

#define MFMA_SPEC() do {                                                    \
    bf16x8 ax_[4], be_[4];                                                  \
    _Pragma("unroll")                                                       \
    for (int i = 0; i < 4; ++i) {                                           \
        const int R_ = r0 + 16 * i + lo;                                    \
        ax_[i] = *(const bf16x8*)(Xt + R_ * S1 + ((hi ^ ((R_ >> 3) & 3)) << 3)); } \
    _Pragma("unroll")                                                       \
    for (int j = 0; j < 4; ++j) {                                           \
        const int R_ = c0 + 16 * j + lo;                                    \
        be_[j] = *(const bf16x8*)(Et + R_ * S1 + ((hi ^ ((R_ >> 3) & 3)) << 3)); } \
    _Pragma("unroll")                                                       \
    for (int i = 0; i < 4; ++i)                                             \
    _Pragma("unroll")                                                       \
    for (int j = 0; j < 4; ++j)                                             \
        acc[i][j] = __builtin_amdgcn_mfma_f32_16x16x32_bf16(ax_[i], be_[j], acc[i][j], 0, 0, 0); \
    } while (0)

    f32x4 acc[4][4] = {};

    ISSUE_SPEC(e0, x0, 0);
    BAR();   // Ms visible before first pack

    ISSUE_SPEC(e1, x1, 1); PACK_SPEC(e0, x0, 0); BAR(); MFMA_SPEC(); BAR();
    ISSUE_SPEC(e0, x0, 2); PACK_SPEC(e1, x1, 1); BAR(); MFMA_SPEC(); BAR();
    ISSUE_SPEC(e1, x1, 3); PACK_SPEC(e0, x0, 2); BAR(); MFMA_SPEC(); BAR();
    ISSUE_SPEC(e0, x0, 4); PACK_SPEC(e1, x1, 3); BAR(); MFMA_SPEC(); BAR();
    PACK_SPEC(e0, x0, 4); BAR(); MFMA_SPEC();

    // epilogue: streamed stores of the private partial tile [d][k]
    float* sg = scr + (size_t)bid * ND * NK;
#pragma unroll
    for (int i = 0; i < 4; ++i)
#pragma unroll
        for (int j = 0; j < 4; ++j)
#pragma unroll
            for (int t = 0; t < 4; ++t) {
                const int dd = r0 + 16 * i + hi * 4 + t;
                const int kk = c0 + 16 * j + lo;
                sg[dd * NK + kk] = acc[i][j][t];
            }
#undef ISSUE_SPEC
#undef PACK_SPEC
#undef MFMA_SPEC
}

// ---------------------------------------------------------------------------
// Kernel 2: reduce 125 partials + apply exp(-lambda*t), write bf16 Yt[g][d][k]
// XCD-pinned (g = bid&7): each XCD reduces the slabs its own k_spec blocks
// wrote -> L2-local reads instead of cross-XCD LLC.
// ---------------------------------------------------------------------------
__global__ __launch_bounds__(256) void k_coef(const float* __restrict__ scr,
                                              const float* __restrict__ evals,
                                              const float* __restrict__ dt,
                                              short* __restrict__ Yt) {
    const int bid = blockIdx.x;                       // 512
    const int g   = bid & 7;
    const int rem = (bid >> 3) * 256 + threadIdx.x;   // 0..16383
    const int d   = rem >> 7;
    const int k   = rem & 127;
    const float* p = scr + (size_t)g * ND * NK + rem;
    float s = 0.f;
#pragma unroll 25
    for (int c = 0; c < NCH; ++c)
        s += p[(size_t)c * 8 * ND * NK];
    const float t = fmaxf(dt[d], 1e-8f);
    Yt[(size_t)g * ND * NK + rem] = bf16r(__expf(-evals[g * NK + k] * t) * s);
}

// ---------------------------------------------------------------------------
// Kernel 3: out[v,d] = sum_k E[v,k] * Yt[g][d][k]
// Contiguous 320-row span per block (63 blocks/graph, XCD-pinned), 5 tiles of
// 64 rows, 2-deep issue-ahead ping-pong. Raw barriers keep the issued-ahead
// tile loads in flight across the MFMA phases (counted vmcnt, never drain-0).
// ---------------------------------------------------------------------------
#define TV    64
#define TPB   5
#define VSPAN (TV * TPB)                    // 320
#define NBLK  ((VG + VSPAN - 1) / VSPAN)    // 63

__global__ __launch_bounds__(256) void k_out(const float* __restrict__ evecs,
                                             const short* __restrict__ Yt,
                                             float* __restrict__ out) {
    const int bid    = blockIdx.x;          // 504 = 63 spans x 8 graphs
    const int g      = bid & 7;
    const int slot   = bid >> 3;
    const int v_base = slot * VSPAN;

    const float* eg = evecs + (size_t)g * VG * NK;
    float*       og = out   + (size_t)g * VG * ND;
    const short* yg = Yt    + (size_t)g * ND * NK;

    __shared__ short Bs[128 * 128];     // Yt [d][k] swizzled, staged once
    __shared__ short As[2][TV * 128];   // E tiles [v][k] swizzled, dbuf

    const int tid  = threadIdx.x;
    const int vrow = tid >> 2;   // 0..63: row within tile
    const int q4   = tid & 3;    // column quarter (32 cols)

    float4 ldA[8], ldB[8];

#define ISSUE_OUT(BUF, t) do {                                              \
    const int tv0_ = v_base + (t) * TV;                                     \
    if (tv0_ < VG) {                                                        \
        const int rows_ = (VG - tv0_ < TV) ? (VG - tv0_) : TV;              \
        const int vc_   = vrow < rows_ ? vrow : rows_ - 1;                  \
        const float* s_ = eg + (size_t)(tv0_ + vc_) * NK + q4 * 32;         \
        _Pragma("unroll")                                                   \
        for (int f = 0; f < 8; ++f) BUF[f] = *(const float4*)(s_ + 4 * f);  \
    } } while (0)

#define WRITE_OUT(BUF, t) do {                                              \
    if (v_base + (t) * TV < VG) {                                           \
        short* A_ = As[(t) & 1];                                            \
        _Pragma("unroll")                                                   \
        for (int h = 0; h < 4; ++h) {                                       \
            uint4 u_;                                                       \
            u_.x = cvtpk(BUF[2 * h].x, BUF[2 * h].y);                       \
            u_.y = cvtpk(BUF[2 * h].z, BUF[2 * h].w);                       \
            u_.z = cvtpk(BUF[2 * h + 1].x, BUF[2 * h + 1].y);               \
            u_.w = cvtpk(BUF[2 * h + 1].z, BUF[2 * h + 1].w);               \
            const int g8_ = q4 * 4 + h;                                     \
            *(uint4*)(A_ + vrow * 128 + ((g8_ ^ (vrow & 7)) << 3)) = u_;    \
        } } } while (0)

    // prologue: Bs global loads FIRST (oldest in vmcnt FIFO), then tiles 0,1
    uint4 bq[8];
#pragma unroll
    for (int it = 0; it < 8; ++it)
        bq[it] = *(const uint4*)(yg + (it * 256 + tid) * 8);
    ISSUE_OUT(ldA, 0);
    ISSUE_OUT(ldB, 1);
#pragma unroll
    for (int it = 0; it < 8; ++it) {
        const int s16 = it * 256 + tid;
        const int rr  = s16 >> 4, gq = s16 & 15;
        *(uint4*)(Bs + rr * 128 + ((gq ^ (rr & 7)) << 3)) = bq[it];
    }
    WRITE_OUT(ldA, 0);   // waits Bs+tile0 loads; tile1 stays in flight
    BAR();

    const int l  = tid & 63;
    const int w  = tid >> 6;
    const int lo = l & 15, hi = l >> 4;
    const int r0 = (w & 1) * 32, c0 = (w >> 1) * 64;  // 32x64 per wave

#define MFMA_OUT(t) do {                                                    \
    const int tv0_ = v_base + (t) * TV;                                     \
    if (tv0_ < VG) {                                                        \
        const int rows_ = (VG - tv0_ < TV) ? (VG - tv0_) : TV;              \
        const short* A_ = As[(t) & 1];                                      \
        f32x4 acc[2][4] = {};                                               \
        _Pragma("unroll")                                                   \
        for (int ks = 0; ks < 4; ++ks) {                                    \
            bf16x8 af_[2], bv_[4];                                          \
            _Pragma("unroll")                                               \
            for (int i = 0; i < 2; ++i) {                                   \
                const int R_ = r0 + 16 * i + lo;                            \
                af_[i] = *(const bf16x8*)(A_ + R_ * 128 + ((((ks << 2) + hi) ^ (R_ & 7)) << 3)); } \
            _Pragma("unroll")                                               \
            for (int j = 0; j < 4; ++j) {                                   \
                const int D_ = c0 + 16 * j + lo;                            \
                bv_[j] = *(const bf16x8*)(Bs + D_ * 128 + ((((ks << 2) + hi) ^ (D_ & 7)) << 3)); } \
            _Pragma("unroll")                                               \
            for (int i = 0; i < 2; ++i)                                     \
            _Pragma("unroll")                                               \
            for (int j = 0; j < 4; ++j)                                     \
                acc[i][j] = __builtin_amdgcn_mfma_f32_16x16x32_bf16(af_[i], bv_[j], acc[i][j], 0, 0, 0); \
        }                                                                   \
        _Pragma("unroll")                                                   \
        for (int i = 0; i < 2; ++i)                                         \
        _Pragma("unroll")                                                   \
        for (int j = 0; j < 4; ++j)                                         \
        _Pragma("unroll")                                                   \
        for (int u = 0; u < 4; ++u) {                                       \
            const int vv_ = r0 + 16 * i + hi * 4 + u;                       \
            if (vv_ < rows_)                                                \
                og[(size_t)(tv0_ + vv_) * ND + c0 + 16 * j + lo] = acc[i][j][u]; \
        } } } while (0)

    // iter ti: issue tile ti+2 into the buffer freed last iter, compute tile
    // ti, ds-write tile ti+1, barrier.
    ISSUE_OUT(ldA, 2); MFMA_OUT(0); WRITE_OUT(ldB, 1); BAR();
    ISSUE_OUT(ldB, 3); MFMA_OUT(1); WRITE_OUT(ldA, 2); BAR();
    ISSUE_OUT(ldA, 4); MFMA_OUT(2); WRITE_OUT(ldB, 3); BAR();
                       MFMA_OUT(3); WRITE_OUT(ldA, 4); BAR();
                       MFMA_OUT(4);
#undef ISSUE_OUT
#undef WRITE_OUT
#undef MFMA_OUT
}

extern "C" void kernel_launch(void* const* d_in, const int* in_sizes, int n_in,
                              void* d_out, int out_size, void* d_ws, size_t ws_size,
                              hipStream_t stream) {
    const float* x     = (const float*)d_in[0];
    const float* mass  = (const float*)d_in[1];
    const float* evals = (const float*)d_in[2];
    const float* evecs = (const float*)d_in[3];
    const float* dt    = (const float*)d_in[4];
    // d_in[5] = batch (unused: equal-sized graphs), d_in[6] = bs (compile-time 8)
    float* out = (float*)d_out;

    // partials live in the OUTPUT buffer (64MB <= 82MB), fully overwritten by
    // k_out afterwards; Yt lives in the workspace (256KB)
    float* scr = out;
    short* Yt  = (short*)d_ws;

    k_spec<<<NCH * BGR, 256, 0, stream>>>(x, mass, evecs, scr);
    k_coef<<<(BGR * ND * NK) / 256, 256, 0, stream>>>(scr, evals, dt, Yt);
    k_out<<<NBLK * BGR, 256, 0, stream>>>(evecs, Yt, out);
}